// Round 13
// baseline (511.413 us; speedup 1.0000x reference)
//
#include <hip/hip_runtime.h>
#include <hip/hip_bf16.h>

typedef __attribute__((ext_vector_type(8))) short bf16x8;
typedef __attribute__((ext_vector_type(16))) float f32x16;
typedef __attribute__((ext_vector_type(4))) unsigned int u32x4;

#define MFMA32(a, b, c) __builtin_amdgcn_mfma_f32_32x32x16_bf16((a), (b), (c), 0, 0, 0)

static __device__ __forceinline__ unsigned int pkbf(float lo, float hi) {
  unsigned int r;
  asm("v_cvt_pk_bf16_f32 %0, %1, %2" : "=v"(r) : "v"(lo), "v"(hi));
  return r;
}

static __device__ __forceinline__ bf16x8 u4_to_bf8(u32x4 u) {
  union { u32x4 u; bf16x8 b; } cv;
  cv.u = u;
  return cv.b;
}

static __device__ __forceinline__ f32x16 z16() {
  f32x16 z;
#pragma unroll
  for (int i = 0; i < 16; ++i) z[i] = 0.0f;
  return z;
}

// Convert one 32x32 MFMA C-tile (value at [row=(r&3)+8*(r>>2)+4*hi][col=lane&31])
// into two bf16 frags with k-runs taken from the ROW dim: f0 = rows 8*hi+{0..7},
// f1 = rows 16+8*hi+{0..7}, column (lane&31) preserved.
static __device__ __forceinline__ void tile2frag(const f32x16 t, int hi,
                                                 bf16x8* f0, bf16x8* f1) {
  unsigned int a0 = pkbf(t[0], t[1]), a1 = pkbf(t[2], t[3]);
  unsigned int b0 = pkbf(t[4], t[5]), b1 = pkbf(t[6], t[7]);
  unsigned int c0 = pkbf(t[8], t[9]), c1 = pkbf(t[10], t[11]);
  unsigned int d0 = pkbf(t[12], t[13]), d1 = pkbf(t[14], t[15]);
  unsigned int sa0 = __shfl_xor((int)a0, 32), sa1 = __shfl_xor((int)a1, 32);
  unsigned int sb0 = __shfl_xor((int)b0, 32), sb1 = __shfl_xor((int)b1, 32);
  unsigned int sc0 = __shfl_xor((int)c0, 32), sc1 = __shfl_xor((int)c1, 32);
  unsigned int sd0 = __shfl_xor((int)d0, 32), sd1 = __shfl_xor((int)d1, 32);
  u32x4 fa, fb;
  fa[0] = hi ? sb0 : a0; fa[1] = hi ? sb1 : a1;
  fa[2] = hi ? b0 : sa0; fa[3] = hi ? b1 : sa1;
  fb[0] = hi ? sd0 : c0; fb[1] = hi ? sd1 : c1;
  fb[2] = hi ? d0 : sc0; fb[3] = hi ? d1 : sc1;
  *f0 = u4_to_bf8(fa);
  *f1 = u4_to_bf8(fb);
}

// 64x64x512 GEMM producing 4 C-tiles, with register-double-buffered weight loads
// (batches of 4 k-steps: 8 global loads in flight under each 16-MFMA group) and
// batched LDS x-reads. Slots c[td][tq]; XFIRST picks MFMA operand order.
template <int XFIRST>
static __device__ __forceinline__ void gemm4(
    const unsigned short* __restrict__ wp,   // pre-offset by lane*8
    const unsigned short* xr0, const unsigned short* xr1, int sw, int hi,
    f32x16& c00, f32x16& c01, f32x16& c10, f32x16& c11) {
  bf16x8 wbuf[2][2][4];  // [buf][stream][j] — all indices compile-time
#pragma unroll
  for (int j = 0; j < 4; ++j) {
    wbuf[0][0][j] = *reinterpret_cast<const bf16x8*>(wp + j * 512);
    wbuf[0][1][j] = *reinterpret_cast<const bf16x8*>(wp + 16384 + j * 512);
  }
#pragma unroll
  for (int kb = 0; kb < 8; ++kb) {
    const int cur = kb & 1, nxt = cur ^ 1;
    if (kb < 7) {
#pragma unroll
      for (int j = 0; j < 4; ++j) {
        wbuf[nxt][0][j] =
            *reinterpret_cast<const bf16x8*>(wp + (kb * 4 + 4 + j) * 512);
        wbuf[nxt][1][j] =
            *reinterpret_cast<const bf16x8*>(wp + 16384 + (kb * 4 + 4 + j) * 512);
      }
    }
    bf16x8 xb0[4], xb1[4];
#pragma unroll
    for (int j = 0; j < 4; ++j) {
      const int eo = 8 * hi + 16 * (kb * 4 + j);
      xb0[j] = *reinterpret_cast<const bf16x8*>(xr0 + (eo ^ sw));
      xb1[j] = *reinterpret_cast<const bf16x8*>(xr1 + (eo ^ sw));
    }
    __builtin_amdgcn_s_setprio(1);
#pragma unroll
    for (int j = 0; j < 4; ++j) {
      if (XFIRST) {
        c00 = MFMA32(xb0[j], wbuf[cur][0][j], c00);
        c01 = MFMA32(xb1[j], wbuf[cur][0][j], c01);
        c10 = MFMA32(xb0[j], wbuf[cur][1][j], c10);
        c11 = MFMA32(xb1[j], wbuf[cur][1][j], c11);
      } else {
        c00 = MFMA32(wbuf[cur][0][j], xb0[j], c00);
        c01 = MFMA32(wbuf[cur][0][j], xb1[j], c01);
        c10 = MFMA32(wbuf[cur][1][j], xb0[j], c10);
        c11 = MFMA32(wbuf[cur][1][j], xb1[j], c11);
      }
    }
    __builtin_amdgcn_s_setprio(0);
  }
}

// Scale + bias/mask + softmax for one query tile. A lane holds only HALF the keys
// (hi-interleaved rows); lane l^32 holds the complement -> combine via shfl_xor(32).
static __device__ __forceinline__ float sm_tp(f32x16& t0, f32x16& t1,
                                              const float* BmRow, int swz, int hi) {
#pragma unroll
  for (int q2 = 0; q2 < 4; ++q2) {
    float4 b0 = *reinterpret_cast<const float4*>(BmRow + ((8 * q2 + 4 * hi) ^ swz));
    float4 b1 = *reinterpret_cast<const float4*>(BmRow + ((32 + 8 * q2 + 4 * hi) ^ swz));
    t0[4 * q2 + 0] = fmaf(t0[4 * q2 + 0], 0.125f, b0.x);
    t0[4 * q2 + 1] = fmaf(t0[4 * q2 + 1], 0.125f, b0.y);
    t0[4 * q2 + 2] = fmaf(t0[4 * q2 + 2], 0.125f, b0.z);
    t0[4 * q2 + 3] = fmaf(t0[4 * q2 + 3], 0.125f, b0.w);
    t1[4 * q2 + 0] = fmaf(t1[4 * q2 + 0], 0.125f, b1.x);
    t1[4 * q2 + 1] = fmaf(t1[4 * q2 + 1], 0.125f, b1.y);
    t1[4 * q2 + 2] = fmaf(t1[4 * q2 + 2], 0.125f, b1.z);
    t1[4 * q2 + 3] = fmaf(t1[4 * q2 + 3], 0.125f, b1.w);
  }
  float mx = t0[0];
#pragma unroll
  for (int r = 1; r < 16; ++r) mx = fmaxf(mx, t0[r]);
#pragma unroll
  for (int r = 0; r < 16; ++r) mx = fmaxf(mx, t1[r]);
  mx = fmaxf(mx, __shfl_xor(mx, 32));
  float sum = 0.f;
#pragma unroll
  for (int r = 0; r < 16; ++r) { t0[r] = __expf(t0[r] - mx); sum += t0[r]; }
#pragma unroll
  for (int r = 0; r < 16; ++r) { t1[r] = __expf(t1[r] - mx); sum += t1[r]; }
  sum += __shfl_xor(sum, 32);
  return 1.0f / sum;
}

// Pack fp32 weights -> bf16 frag-order: 32 blocks of [64][512] (Wq h0-7, Wk h0-7,
// Wv h0-7, Wo w0-7); cell (td,ke,lane)*8 = W[32*td+l31][16*ke+8*hi+{0..7}].
__global__ __launch_bounds__(256) void prep_weights(
    const float* __restrict__ Wq, const float* __restrict__ Wk,
    const float* __restrict__ Wv, const float* __restrict__ Wo,
    unsigned short* __restrict__ dst) {
  int i = blockIdx.x * 256 + threadIdx.x;   // 131072 cells x 8 elems
  int blk = i >> 12;
  int c = i & 4095;
  int td = c >> 11;
  int ke = (c >> 6) & 31;
  int lane = c & 63;
  int hi = lane >> 5, l31 = lane & 31;
  int row = 32 * td + l31;
  int e = 16 * ke + 8 * hi;
  int seg = blk >> 3, sub = blk & 7;
  const float* base = (seg == 0) ? Wq : (seg == 1) ? Wk : (seg == 2) ? Wv : Wo;
  const float* src = base + (size_t)(sub * 64 + row) * 512 + e;
  float4 v0 = reinterpret_cast<const float4*>(src)[0];
  float4 v1 = reinterpret_cast<const float4*>(src)[1];
  u32x4 o;
  o[0] = pkbf(v0.x, v0.y); o[1] = pkbf(v0.z, v0.w);
  o[2] = pkbf(v1.x, v1.y); o[3] = pkbf(v1.z, v1.w);
  *reinterpret_cast<u32x4*>(dst + (size_t)blk * 32768 + c * 8) = o;
}

// One block per window (2048 blocks), 256 threads = 4 waves; wave w handles
// heads {w, w+4}. R staged in the window's own out slot (floats 0..16383).
// Max simultaneous acc tiles = 4 (64 AGPR) KERNEL-WIDE, so accum_offset can
// sit at 64 and the arch side gets ~192 of the 2-wave/SIMD 256-reg budget —
// room for gemm4's deep load pipeline without spilling.
__global__ __launch_bounds__(256, 1) void swin_fused(
    const float* __restrict__ patches,
    const float* __restrict__ bq, const float* __restrict__ bk,
    const float* __restrict__ bv, const float* __restrict__ bo,
    const float* __restrict__ posb,
    const unsigned short* __restrict__ Wbf,
    float* __restrict__ out) {
  __shared__ unsigned short Xs[64 * 512];    // X bf16, swizzled
  __shared__ float Bm[64 * 64];              // bias+mask, granule-swizzled

  const int tid = threadIdx.x;
  const int bid = blockIdx.x;                // ((b*16+y)*16+x)
  const int wxi = bid & 15;
  const int wyi = (bid >> 4) & 15;
  const int w = tid >> 6;                    // wave 0..3
  const int lane = tid & 63;
  const int l31 = lane & 31;
  const int hi = lane >> 5;

  // ---- Phase A: stage X (fp32->bf16, 5-bit granule swizzle) + build Bm ----
  const float* Xg = patches + (size_t)bid * 32768;
#pragma unroll
  for (int it = 0; it < 16; ++it) {
    int p = it * 4 + w;
    int e0 = lane << 3;
    const float4* gp = reinterpret_cast<const float4*>(Xg + p * 512 + e0);
    float4 v0 = gp[0], v1 = gp[1];
    u32x4 xv;
    xv[0] = pkbf(v0.x, v0.y); xv[1] = pkbf(v0.z, v0.w);
    xv[2] = pkbf(v1.x, v1.y); xv[3] = pkbf(v1.z, v1.w);
    *reinterpret_cast<u32x4*>(Xs + p * 512 + (e0 ^ ((p & 31) << 3))) = xv;
  }
#pragma unroll
  for (int ii = 0; ii < 16; ++ii) {
    int i = ii * 256 + tid;
    int p = i >> 6, k = i & 63;
    int pr = p >> 3, pc = p & 7, kr = k >> 3, kc = k & 7;
    float b = posb[(pr - kr + 7) * 15 + (pc - kc + 7)];
    bool mk = ((wyi == 15) && ((pr < 4) != (kr < 4))) ||
              ((wxi == 15) && ((pc < 4) != (kc < 4)));
    Bm[p * 64 + (k ^ ((p & 15) << 2))] = mk ? -1e30f : b;
  }
  __syncthreads();

  // R staging area: first 64 KiB (32768 shorts = floats 0..16383) of the slot.
  unsigned short* Rws = reinterpret_cast<unsigned short*>(out) + (size_t)bid * 65536;

  const int sw = l31 << 3;
  const unsigned short* xr0 = Xs + l31 * 512;
  const unsigned short* xr1 = Xs + (l31 + 32) * 512;
  const int bswz = (l31 & 15) << 2;

#pragma unroll
  for (int hh = 0; hh < 2; ++hh) {
    const int h = w + 4 * hh;
    // Phase B: K, Q projections (gemm4, W-first; c[td][tq])
    bf16x8 kf[2][4], qf[2][4];
    {
      f32x16 c00 = z16(), c01 = z16(), c10 = z16(), c11 = z16();
      gemm4<0>(Wbf + (size_t)(8 + h) * 32768 + lane * 8, xr0, xr1, sw, hi,
               c00, c01, c10, c11);
      const float* bg = bk + h * 64;
#pragma unroll
      for (int q2 = 0; q2 < 4; ++q2) {
        float4 b0 = *reinterpret_cast<const float4*>(bg + 8 * q2 + 4 * hi);
        float4 b1 = *reinterpret_cast<const float4*>(bg + 32 + 8 * q2 + 4 * hi);
        c00[4 * q2 + 0] += b0.x; c00[4 * q2 + 1] += b0.y;
        c00[4 * q2 + 2] += b0.z; c00[4 * q2 + 3] += b0.w;
        c01[4 * q2 + 0] += b0.x; c01[4 * q2 + 1] += b0.y;
        c01[4 * q2 + 2] += b0.z; c01[4 * q2 + 3] += b0.w;
        c10[4 * q2 + 0] += b1.x; c10[4 * q2 + 1] += b1.y;
        c10[4 * q2 + 2] += b1.z; c10[4 * q2 + 3] += b1.w;
        c11[4 * q2 + 0] += b1.x; c11[4 * q2 + 1] += b1.y;
        c11[4 * q2 + 2] += b1.z; c11[4 * q2 + 3] += b1.w;
      }
      tile2frag(c00, hi, &kf[0][0], &kf[0][1]);
      tile2frag(c10, hi, &kf[0][2], &kf[0][3]);
      tile2frag(c01, hi, &kf[1][0], &kf[1][1]);
      tile2frag(c11, hi, &kf[1][2], &kf[1][3]);
    }
    {
      f32x16 c00 = z16(), c01 = z16(), c10 = z16(), c11 = z16();
      gemm4<0>(Wbf + (size_t)(0 + h) * 32768 + lane * 8, xr0, xr1, sw, hi,
               c00, c01, c10, c11);
      const float* bg = bq + h * 64;
#pragma unroll
      for (int q2 = 0; q2 < 4; ++q2) {
        float4 b0 = *reinterpret_cast<const float4*>(bg + 8 * q2 + 4 * hi);
        float4 b1 = *reinterpret_cast<const float4*>(bg + 32 + 8 * q2 + 4 * hi);
        c00[4 * q2 + 0] += b0.x; c00[4 * q2 + 1] += b0.y;
        c00[4 * q2 + 2] += b0.z; c00[4 * q2 + 3] += b0.w;
        c01[4 * q2 + 0] += b0.x; c01[4 * q2 + 1] += b0.y;
        c01[4 * q2 + 2] += b0.z; c01[4 * q2 + 3] += b0.w;
        c10[4 * q2 + 0] += b1.x; c10[4 * q2 + 1] += b1.y;
        c10[4 * q2 + 2] += b1.z; c10[4 * q2 + 3] += b1.w;
        c11[4 * q2 + 0] += b1.x; c11[4 * q2 + 1] += b1.y;
        c11[4 * q2 + 2] += b1.z; c11[4 * q2 + 3] += b1.w;
      }
      tile2frag(c00, hi, &qf[0][0], &qf[0][1]);
      tile2frag(c10, hi, &qf[0][2], &qf[0][3]);
      tile2frag(c01, hi, &qf[1][0], &qf[1][1]);
      tile2frag(c11, hi, &qf[1][2], &qf[1][3]);
    }

    // Phase C: S^T = K' Q'^T (4 parallel tiles = 64 AGPR) + softmax
    f32x16 s00 = z16(), s01 = z16(), s10 = z16(), s11 = z16();  // s[tk][tp]
    __builtin_amdgcn_s_setprio(1);
#pragma unroll
    for (int kd = 0; kd < 4; ++kd) {
      s00 = MFMA32(kf[0][kd], qf[0][kd], s00);
      s01 = MFMA32(kf[0][kd], qf[1][kd], s01);
      s10 = MFMA32(kf[1][kd], qf[0][kd], s10);
      s11 = MFMA32(kf[1][kd], qf[1][kd], s11);
    }
    __builtin_amdgcn_s_setprio(0);
    float sinv0 = sm_tp(s00, s10, Bm + l31 * 64, bswz, hi);
    float sinv1 = sm_tp(s01, s11, Bm + (l31 + 32) * 64, bswz, hi);
    bf16x8 pf[2][4];
    tile2frag(s00, hi, &pf[0][0], &pf[0][1]);
    tile2frag(s10, hi, &pf[0][2], &pf[0][3]);
    tile2frag(s01, hi, &pf[1][0], &pf[1][1]);
    tile2frag(s11, hi, &pf[1][2], &pf[1][3]);

    // Phase D: V projection (gemm4, X-first; slots c[td][tq])
    bf16x8 vf[2][4];   // vf[td][ks]
    {
      f32x16 c00 = z16(), c01 = z16(), c10 = z16(), c11 = z16();
      gemm4<1>(Wbf + (size_t)(16 + h) * 32768 + lane * 8, xr0, xr1, sw, hi,
               c00, c01, c10, c11);
      float bv0 = bv[h * 64 + l31];
      float bv1 = bv[h * 64 + l31 + 32];
#pragma unroll
      for (int r = 0; r < 16; ++r) {
        c00[r] += bv0; c01[r] += bv0;
        c10[r] += bv1; c11[r] += bv1;
      }
      tile2frag(c00, hi, &vf[0][0], &vf[0][1]);
      tile2frag(c01, hi, &vf[0][2], &vf[0][3]);
      tile2frag(c10, hi, &vf[1][0], &vf[1][1]);
      tile2frag(c11, hi, &vf[1][2], &vf[1][3]);
    }

    // Phase E: R^T = V^T @ P (4 parallel tiles), normalize, store frags to Rws.
    // Rws cells: [(tq*32 + ke)*64 + lane]*8 = R[p=32*tq+l31][hd=16*ke+8*hi+..];
    // this head's ke = h*4 + {0..3}.
    f32x16 r00 = z16(), r01 = z16(), r10 = z16(), r11 = z16();  // r[td][tp]
    __builtin_amdgcn_s_setprio(1);
#pragma unroll
    for (int ks = 0; ks < 4; ++ks) {
      r00 = MFMA32(vf[0][ks], pf[0][ks], r00); r01 = MFMA32(vf[0][ks], pf[1][ks], r01);
      r10 = MFMA32(vf[1][ks], pf[0][ks], r10); r11 = MFMA32(vf[1][ks], pf[1][ks], r11);
    }
    __builtin_amdgcn_s_setprio(0);
#pragma unroll
    for (int r = 0; r < 16; ++r) {
      r00[r] *= sinv0; r10[r] *= sinv0;
      r01[r] *= sinv1; r11[r] *= sinv1;
    }
    {
      bf16x8 f0, f1;
      unsigned short* rl = Rws + lane * 8;
      tile2frag(r00, hi, &f0, &f1);   // td0, tp0 -> tq=0, ke = h*4 + {0,1}
      *reinterpret_cast<bf16x8*>(rl + (h * 4 + 0) * 512) = f0;
      *reinterpret_cast<bf16x8*>(rl + (h * 4 + 1) * 512) = f1;
      tile2frag(r01, hi, &f0, &f1);   // td0, tp1 -> tq=1
      *reinterpret_cast<bf16x8*>(rl + 16384 + (h * 4 + 0) * 512) = f0;
      *reinterpret_cast<bf16x8*>(rl + 16384 + (h * 4 + 1) * 512) = f1;
      tile2frag(r10, hi, &f0, &f1);   // td1, tp0 -> ke = h*4 + {2,3}
      *reinterpret_cast<bf16x8*>(rl + (h * 4 + 2) * 512) = f0;
      *reinterpret_cast<bf16x8*>(rl + (h * 4 + 3) * 512) = f1;
      tile2frag(r11, hi, &f0, &f1);   // td1, tp1
      *reinterpret_cast<bf16x8*>(rl + 16384 + (h * 4 + 2) * 512) = f0;
      *reinterpret_cast<bf16x8*>(rl + 16384 + (h * 4 + 3) * 512) = f1;
    }
  }

  __syncthreads();  // drain R stores + barrier: R visible block-wide

  // ---- Phase F: out = R @ Wo^T (+bo); wave w owns cols 128w..128w+127.
  // Two tq-stages of 4 acc tiles (64 AGPR max). Stage tq=1 writes out rows
  // 32-63 (floats >=16384: no overlap with R staging floats 0..16383) with NO
  // barrier. Stage tq=0 accumulates, then one barrier (all R reads complete),
  // then writes rows 0-31 (which clobber the staging area).
  float* og = out + (size_t)bid * 32768;
  {
    // stage tq = 1
    f32x16 a[2][2];   // [pass][j]
#pragma unroll
    for (int p2 = 0; p2 < 2; ++p2)
#pragma unroll
      for (int j = 0; j < 2; ++j) a[p2][j] = z16();
    const unsigned short* rl = Rws + 16384 + lane * 8;
#pragma unroll
    for (int pass = 0; pass < 2; ++pass) {
      const unsigned short* wp =
          Wbf + (size_t)(24 + 2 * w + pass) * 32768 + lane * 8;
#pragma unroll 4
      for (int kc = 0; kc < 32; ++kc) {
        bf16x8 r1 = *reinterpret_cast<const bf16x8*>(rl + kc * 512);
        bf16x8 wo0 = *reinterpret_cast<const bf16x8*>(wp + kc * 512);
        bf16x8 wo1 = *reinterpret_cast<const bf16x8*>(wp + 16384 + kc * 512);
        a[pass][0] = MFMA32(r1, wo0, a[pass][0]);
        a[pass][1] = MFMA32(r1, wo1, a[pass][1]);
      }
    }
#pragma unroll
    for (int pass = 0; pass < 2; ++pass)
#pragma unroll
      for (int j = 0; j < 2; ++j) {
        int col0 = 128 * w + 64 * pass + 32 * j + l31;
        float bov = bo[col0];
        const f32x16& t = a[pass][j];
#pragma unroll
        for (int r = 0; r < 16; ++r) {
          int p = (r & 3) + 8 * (r >> 2) + 4 * hi + 32;
          og[p * 512 + col0] = t[r] + bov;
        }
      }
  }
  {
    // stage tq = 0
    f32x16 a[2][2];
#pragma unroll
    for (int p2 = 0; p2 < 2; ++p2)
#pragma unroll
      for (int j = 0; j < 2; ++j) a[p2][j] = z16();
    const unsigned short* rl = Rws + lane * 8;
#pragma unroll
    for (int pass = 0; pass < 2; ++pass) {
      const unsigned short* wp =
          Wbf + (size_t)(24 + 2 * w + pass) * 32768 + lane * 8;
#pragma unroll 4
      for (int kc = 0; kc < 32; ++kc) {
        bf16x8 r0 = *reinterpret_cast<const bf16x8*>(rl + kc * 512);
        bf16x8 wo0 = *reinterpret_cast<const bf16x8*>(wp + kc * 512);
        bf16x8 wo1 = *reinterpret_cast<const bf16x8*>(wp + 16384 + kc * 512);
        a[pass][0] = MFMA32(r0, wo0, a[pass][0]);
        a[pass][1] = MFMA32(r0, wo1, a[pass][1]);
      }
    }
    __syncthreads();  // ALL waves done reading R; staging may be overwritten
#pragma unroll
    for (int pass = 0; pass < 2; ++pass)
#pragma unroll
      for (int j = 0; j < 2; ++j) {
        int col0 = 128 * w + 64 * pass + 32 * j + l31;
        float bov = bo[col0];
        const f32x16& t = a[pass][j];
#pragma unroll
        for (int r = 0; r < 16; ++r) {
          int p = (r & 3) + 8 * (r >> 2) + 4 * hi;
          og[p * 512 + col0] = t[r] + bov;
        }
      }
  }
}

extern "C" void kernel_launch(void* const* d_in, const int* in_sizes, int n_in,
                              void* d_out, int out_size, void* d_ws, size_t ws_size,
                              hipStream_t stream) {
  const float* patches = (const float*)d_in[0];
  const float* Wq = (const float*)d_in[1];
  const float* bq = (const float*)d_in[2];
  const float* Wk = (const float*)d_in[3];
  const float* bk = (const float*)d_in[4];
  const float* Wv = (const float*)d_in[5];
  const float* bv = (const float*)d_in[6];
  const float* Wo = (const float*)d_in[7];
  const float* bo = (const float*)d_in[8];
  const float* posb = (const float*)d_in[9];
  // mask (d_in[10]) / bias_idx (d_in[11],[12]) recomputed on device.
  unsigned short* wbf = (unsigned short*)d_ws;   // 2 MiB
  hipLaunchKernelGGL(prep_weights, dim3(512), dim3(256), 0, stream, Wq, Wk, Wv, Wo, wbf);
  hipLaunchKernelGGL(swin_fused, dim3(2048), dim3(256), 0, stream,
                     patches, bq, bk, bv, bo, posb, wbf, (float*)d_out);
}

// Round 14
// 378.911 us; speedup vs baseline: 1.3497x; 1.3497x over previous
//
#include <hip/hip_runtime.h>
#include <hip/hip_bf16.h>

typedef __attribute__((ext_vector_type(8))) short bf16x8;
typedef __attribute__((ext_vector_type(16))) float f32x16;
typedef __attribute__((ext_vector_type(4))) unsigned int u32x4;

#define MFMA32(a, b, c) __builtin_amdgcn_mfma_f32_32x32x16_bf16((a), (b), (c), 0, 0, 0)

static __device__ __forceinline__ unsigned int pkbf(float lo, float hi) {
  unsigned int r;
  asm("v_cvt_pk_bf16_f32 %0, %1, %2" : "=v"(r) : "v"(lo), "v"(hi));
  return r;
}

static __device__ __forceinline__ bf16x8 u4_to_bf8(u32x4 u) {
  union { u32x4 u; bf16x8 b; } cv;
  cv.u = u;
  return cv.b;
}

static __device__ __forceinline__ f32x16 z16() {
  f32x16 z;
#pragma unroll
  for (int i = 0; i < 16; ++i) z[i] = 0.0f;
  return z;
}

// Convert one 32x32 MFMA C-tile (value at [row=(r&3)+8*(r>>2)+4*hi][col=lane&31])
// into two bf16 frags with k-runs taken from the ROW dim: f0 = rows 8*hi+{0..7},
// f1 = rows 16+8*hi+{0..7}, column (lane&31) preserved.
static __device__ __forceinline__ void tile2frag(const f32x16 t, int hi,
                                                 bf16x8* f0, bf16x8* f1) {
  unsigned int a0 = pkbf(t[0], t[1]), a1 = pkbf(t[2], t[3]);
  unsigned int b0 = pkbf(t[4], t[5]), b1 = pkbf(t[6], t[7]);
  unsigned int c0 = pkbf(t[8], t[9]), c1 = pkbf(t[10], t[11]);
  unsigned int d0 = pkbf(t[12], t[13]), d1 = pkbf(t[14], t[15]);
  unsigned int sa0 = __shfl_xor((int)a0, 32), sa1 = __shfl_xor((int)a1, 32);
  unsigned int sb0 = __shfl_xor((int)b0, 32), sb1 = __shfl_xor((int)b1, 32);
  unsigned int sc0 = __shfl_xor((int)c0, 32), sc1 = __shfl_xor((int)c1, 32);
  unsigned int sd0 = __shfl_xor((int)d0, 32), sd1 = __shfl_xor((int)d1, 32);
  u32x4 fa, fb;
  fa[0] = hi ? sb0 : a0; fa[1] = hi ? sb1 : a1;
  fa[2] = hi ? b0 : sa0; fa[3] = hi ? b1 : sa1;
  fb[0] = hi ? sd0 : c0; fb[1] = hi ? sd1 : c1;
  fb[2] = hi ? d0 : sc0; fb[3] = hi ? d1 : sc1;
  *f0 = u4_to_bf8(fa);
  *f1 = u4_to_bf8(fb);
}

// T = (X @ Wg^T + bg)^T via mfma(A=W-frags, B=X rows), 4 parallel C-tiles.
// Wg pre-packed: cell (td,ke,lane)*8.
static __device__ __forceinline__ void projT4(
    const unsigned short* __restrict__ Wg, const float* __restrict__ bg,
    const unsigned short* Xs, int lane, int l31, int hi, bf16x8 frag[2][4]) {
  f32x16 c00 = z16(), c01 = z16(), c10 = z16(), c11 = z16();  // c[td][tq]
  const int sw = l31 << 3;
  const unsigned short* xr0 = Xs + l31 * 512;
  const unsigned short* xr1 = Xs + (l31 + 32) * 512;
  const unsigned short* wp = Wg + lane * 8;
#pragma unroll 4
  for (int ke = 0; ke < 32; ++ke) {
    const int eo = 8 * hi + 16 * ke;
    bf16x8 x0 = *reinterpret_cast<const bf16x8*>(xr0 + (eo ^ sw));
    bf16x8 x1 = *reinterpret_cast<const bf16x8*>(xr1 + (eo ^ sw));
    bf16x8 w0 = *reinterpret_cast<const bf16x8*>(wp + ke * 512);
    bf16x8 w1 = *reinterpret_cast<const bf16x8*>(wp + 16384 + ke * 512);
    c00 = MFMA32(w0, x0, c00); c01 = MFMA32(w0, x1, c01);
    c10 = MFMA32(w1, x0, c10); c11 = MFMA32(w1, x1, c11);
  }
#pragma unroll
  for (int q2 = 0; q2 < 4; ++q2) {
    float4 b0 = *reinterpret_cast<const float4*>(bg + 8 * q2 + 4 * hi);
    float4 b1 = *reinterpret_cast<const float4*>(bg + 32 + 8 * q2 + 4 * hi);
    c00[4 * q2 + 0] += b0.x; c00[4 * q2 + 1] += b0.y;
    c00[4 * q2 + 2] += b0.z; c00[4 * q2 + 3] += b0.w;
    c01[4 * q2 + 0] += b0.x; c01[4 * q2 + 1] += b0.y;
    c01[4 * q2 + 2] += b0.z; c01[4 * q2 + 3] += b0.w;
    c10[4 * q2 + 0] += b1.x; c10[4 * q2 + 1] += b1.y;
    c10[4 * q2 + 2] += b1.z; c10[4 * q2 + 3] += b1.w;
    c11[4 * q2 + 0] += b1.x; c11[4 * q2 + 1] += b1.y;
    c11[4 * q2 + 2] += b1.z; c11[4 * q2 + 3] += b1.w;
  }
  tile2frag(c00, hi, &frag[0][0], &frag[0][1]);
  tile2frag(c10, hi, &frag[0][2], &frag[0][3]);
  tile2frag(c01, hi, &frag[1][0], &frag[1][1]);
  tile2frag(c11, hi, &frag[1][2], &frag[1][3]);
}

// Scale + bias/mask + softmax for one query tile. A lane holds only HALF the keys
// (hi-interleaved rows); lane l^32 holds the complement -> combine via shfl_xor(32).
static __device__ __forceinline__ float sm_tp(f32x16& t0, f32x16& t1,
                                              const float* BmRow, int swz, int hi) {
#pragma unroll
  for (int q2 = 0; q2 < 4; ++q2) {
    float4 b0 = *reinterpret_cast<const float4*>(BmRow + ((8 * q2 + 4 * hi) ^ swz));
    float4 b1 = *reinterpret_cast<const float4*>(BmRow + ((32 + 8 * q2 + 4 * hi) ^ swz));
    t0[4 * q2 + 0] = fmaf(t0[4 * q2 + 0], 0.125f, b0.x);
    t0[4 * q2 + 1] = fmaf(t0[4 * q2 + 1], 0.125f, b0.y);
    t0[4 * q2 + 2] = fmaf(t0[4 * q2 + 2], 0.125f, b0.z);
    t0[4 * q2 + 3] = fmaf(t0[4 * q2 + 3], 0.125f, b0.w);
    t1[4 * q2 + 0] = fmaf(t1[4 * q2 + 0], 0.125f, b1.x);
    t1[4 * q2 + 1] = fmaf(t1[4 * q2 + 1], 0.125f, b1.y);
    t1[4 * q2 + 2] = fmaf(t1[4 * q2 + 2], 0.125f, b1.z);
    t1[4 * q2 + 3] = fmaf(t1[4 * q2 + 3], 0.125f, b1.w);
  }
  float mx = t0[0];
#pragma unroll
  for (int r = 1; r < 16; ++r) mx = fmaxf(mx, t0[r]);
#pragma unroll
  for (int r = 0; r < 16; ++r) mx = fmaxf(mx, t1[r]);
  mx = fmaxf(mx, __shfl_xor(mx, 32));
  float sum = 0.f;
#pragma unroll
  for (int r = 0; r < 16; ++r) { t0[r] = __expf(t0[r] - mx); sum += t0[r]; }
#pragma unroll
  for (int r = 0; r < 16; ++r) { t1[r] = __expf(t1[r] - mx); sum += t1[r]; }
  sum += __shfl_xor(sum, 32);
  return 1.0f / sum;
}

// Pack fp32 weights -> bf16 frag-order: 32 blocks of [64][512] (Wq h0-7, Wk h0-7,
// Wv h0-7, Wo w0-7); cell (td,ke,lane)*8 = W[32*td+l31][16*ke+8*hi+{0..7}].
__global__ __launch_bounds__(256) void prep_weights(
    const float* __restrict__ Wq, const float* __restrict__ Wk,
    const float* __restrict__ Wv, const float* __restrict__ Wo,
    unsigned short* __restrict__ dst) {
  int i = blockIdx.x * 256 + threadIdx.x;   // 131072 cells x 8 elems
  int blk = i >> 12;
  int c = i & 4095;
  int td = c >> 11;
  int ke = (c >> 6) & 31;
  int lane = c & 63;
  int hi = lane >> 5, l31 = lane & 31;
  int row = 32 * td + l31;
  int e = 16 * ke + 8 * hi;
  int seg = blk >> 3, sub = blk & 7;
  const float* base = (seg == 0) ? Wq : (seg == 1) ? Wk : (seg == 2) ? Wv : Wo;
  const float* src = base + (size_t)(sub * 64 + row) * 512 + e;
  float4 v0 = reinterpret_cast<const float4*>(src)[0];
  float4 v1 = reinterpret_cast<const float4*>(src)[1];
  u32x4 o;
  o[0] = pkbf(v0.x, v0.y); o[1] = pkbf(v0.z, v0.w);
  o[2] = pkbf(v1.x, v1.y); o[3] = pkbf(v1.z, v1.w);
  *reinterpret_cast<u32x4*>(dst + (size_t)blk * 32768 + c * 8) = o;
}

// One block per window (2048 blocks), 256 threads = 4 waves; wave w handles
// heads {w, w+4}. R staged in the window's own out slot. Register strategy:
// arch peak <=128 (the (256,2) allocator cap), AGPR <=128 (Phase F 8 tiles).
// Explicit register-dbuf prefetch only in Phases D and F where arch slack
// exists; Phase B relies on compiler scheduling (unroll 4).
__global__ __launch_bounds__(256, 2) void swin_fused(
    const float* __restrict__ patches,
    const float* __restrict__ bq, const float* __restrict__ bk,
    const float* __restrict__ bv, const float* __restrict__ bo,
    const float* __restrict__ posb,
    const unsigned short* __restrict__ Wbf,
    float* __restrict__ out) {
  __shared__ unsigned short Xs[64 * 512];    // X bf16, swizzled
  __shared__ float Bm[64 * 64];              // bias+mask, granule-swizzled

  const int tid = threadIdx.x;
  const int bid = blockIdx.x;                // ((b*16+y)*16+x)
  const int wxi = bid & 15;
  const int wyi = (bid >> 4) & 15;
  const int w = tid >> 6;                    // wave 0..3
  const int lane = tid & 63;
  const int l31 = lane & 31;
  const int hi = lane >> 5;

  // ---- Phase A: stage X (fp32->bf16, 5-bit granule swizzle) + build Bm ----
  const float* Xg = patches + (size_t)bid * 32768;
#pragma unroll
  for (int it = 0; it < 16; ++it) {
    int p = it * 4 + w;
    int e0 = lane << 3;
    const float4* gp = reinterpret_cast<const float4*>(Xg + p * 512 + e0);
    float4 v0 = gp[0], v1 = gp[1];
    u32x4 xv;
    xv[0] = pkbf(v0.x, v0.y); xv[1] = pkbf(v0.z, v0.w);
    xv[2] = pkbf(v1.x, v1.y); xv[3] = pkbf(v1.z, v1.w);
    *reinterpret_cast<u32x4*>(Xs + p * 512 + (e0 ^ ((p & 31) << 3))) = xv;
  }
#pragma unroll
  for (int ii = 0; ii < 16; ++ii) {
    int i = ii * 256 + tid;
    int p = i >> 6, k = i & 63;
    int pr = p >> 3, pc = p & 7, kr = k >> 3, kc = k & 7;
    float b = posb[(pr - kr + 7) * 15 + (pc - kc + 7)];
    bool mk = ((wyi == 15) && ((pr < 4) != (kr < 4))) ||
              ((wxi == 15) && ((pc < 4) != (kc < 4)));
    Bm[p * 64 + (k ^ ((p & 15) << 2))] = mk ? -1e30f : b;
  }
  __syncthreads();

  // R staging area: first 64 KiB (32768 shorts) of this window's out slot.
  unsigned short* Rws = reinterpret_cast<unsigned short*>(out) + (size_t)bid * 65536;

  const int bswz = (l31 & 15) << 2;
#pragma unroll
  for (int hh = 0; hh < 2; ++hh) {
    const int h = w + 4 * hh;
    // Phase B: K, Q projections
    bf16x8 kf[2][4], qf[2][4];
    projT4(Wbf + (size_t)(8 + h) * 32768, bk + h * 64, Xs, lane, l31, hi, kf);
    projT4(Wbf + (size_t)(0 + h) * 32768, bq + h * 64, Xs, lane, l31, hi, qf);

    // Phase C: S^T = K' Q'^T (4 parallel tiles) + softmax
    f32x16 s00 = z16(), s01 = z16(), s10 = z16(), s11 = z16();  // s[tk][tp]
#pragma unroll
    for (int kd = 0; kd < 4; ++kd) {
      s00 = MFMA32(kf[0][kd], qf[0][kd], s00);
      s01 = MFMA32(kf[0][kd], qf[1][kd], s01);
      s10 = MFMA32(kf[1][kd], qf[0][kd], s10);
      s11 = MFMA32(kf[1][kd], qf[1][kd], s11);
    }
    float sinv0 = sm_tp(s00, s10, Bm + l31 * 64, bswz, hi);
    float sinv1 = sm_tp(s01, s11, Bm + (l31 + 32) * 64, bswz, hi);
    bf16x8 pf[2][4];
    tile2frag(s00, hi, &pf[0][0], &pf[0][1]);
    tile2frag(s10, hi, &pf[0][2], &pf[0][3]);
    tile2frag(s01, hi, &pf[1][0], &pf[1][1]);
    tile2frag(s11, hi, &pf[1][2], &pf[1][3]);

    // Phase D: V projection with explicit batch-2 register-dbuf weight
    // prefetch (wb = 32 arch regs; ~4 KiB in flight under each 8-MFMA group).
    bf16x8 vf[2][4];   // vf[td][ks]
    {
      f32x16 v00 = z16(), v01 = z16(), v10 = z16(), v11 = z16();  // v[tq][td]
      const int sw = l31 << 3;
      const unsigned short* xr0 = Xs + l31 * 512;
      const unsigned short* xr1 = Xs + (l31 + 32) * 512;
      const unsigned short* wp = Wbf + (size_t)(16 + h) * 32768 + lane * 8;
      bf16x8 wb[2][2][2];  // [buf][ke-in-batch][stream] — compile-time indices
#pragma unroll
      for (int j = 0; j < 2; ++j) {
        wb[0][j][0] = *reinterpret_cast<const bf16x8*>(wp + j * 512);
        wb[0][j][1] = *reinterpret_cast<const bf16x8*>(wp + 16384 + j * 512);
      }
#pragma unroll
      for (int kb = 0; kb < 16; ++kb) {
        const int cur = kb & 1, nxt = cur ^ 1;
        if (kb < 15) {
#pragma unroll
          for (int j = 0; j < 2; ++j) {
            wb[nxt][j][0] =
                *reinterpret_cast<const bf16x8*>(wp + (kb * 2 + 2 + j) * 512);
            wb[nxt][j][1] = *reinterpret_cast<const bf16x8*>(
                wp + 16384 + (kb * 2 + 2 + j) * 512);
          }
        }
#pragma unroll
        for (int j = 0; j < 2; ++j) {
          const int eo = 8 * hi + 16 * (kb * 2 + j);
          bf16x8 x0 = *reinterpret_cast<const bf16x8*>(xr0 + (eo ^ sw));
          bf16x8 x1 = *reinterpret_cast<const bf16x8*>(xr1 + (eo ^ sw));
          v00 = MFMA32(x0, wb[cur][j][0], v00);
          v01 = MFMA32(x0, wb[cur][j][1], v01);
          v10 = MFMA32(x1, wb[cur][j][0], v10);
          v11 = MFMA32(x1, wb[cur][j][1], v11);
        }
      }
      float bv0 = bv[h * 64 + l31];
      float bv1 = bv[h * 64 + l31 + 32];
#pragma unroll
      for (int r = 0; r < 16; ++r) {
        v00[r] += bv0; v10[r] += bv0;
        v01[r] += bv1; v11[r] += bv1;
      }
      tile2frag(v00, hi, &vf[0][0], &vf[0][1]);
      tile2frag(v10, hi, &vf[0][2], &vf[0][3]);
      tile2frag(v01, hi, &vf[1][0], &vf[1][1]);
      tile2frag(v11, hi, &vf[1][2], &vf[1][3]);
    }

    // Phase E: R^T = V^T @ P (4 parallel tiles), normalize, frag, store to Rws.
    // Rws layout (weight-style cells): [tq][ke][lane]*8 holding
    // R[p=32*tq+l31][hd=16*ke+8*hi+{0..7}]; this head's ke = h*4 + {0..3}.
    f32x16 r00 = z16(), r01 = z16(), r10 = z16(), r11 = z16();  // r[td][tp]
#pragma unroll
    for (int ks = 0; ks < 4; ++ks) {
      r00 = MFMA32(vf[0][ks], pf[0][ks], r00); r01 = MFMA32(vf[0][ks], pf[1][ks], r01);
      r10 = MFMA32(vf[1][ks], pf[0][ks], r10); r11 = MFMA32(vf[1][ks], pf[1][ks], r11);
    }
#pragma unroll
    for (int r = 0; r < 16; ++r) {
      r00[r] *= sinv0; r10[r] *= sinv0;
      r01[r] *= sinv1; r11[r] *= sinv1;
    }
    {
      bf16x8 f0, f1;
      unsigned short* rl = Rws + lane * 8;
      tile2frag(r00, hi, &f0, &f1);   // td0, tp0 -> ke = h*4 + {0,1}, tq=0
      *reinterpret_cast<bf16x8*>(rl + (h * 4 + 0) * 512) = f0;
      *reinterpret_cast<bf16x8*>(rl + (h * 4 + 1) * 512) = f1;
      tile2frag(r01, hi, &f0, &f1);   // td0, tp1 -> tq=1
      *reinterpret_cast<bf16x8*>(rl + 16384 + (h * 4 + 0) * 512) = f0;
      *reinterpret_cast<bf16x8*>(rl + 16384 + (h * 4 + 1) * 512) = f1;
      tile2frag(r10, hi, &f0, &f1);   // td1, tp0 -> ke = h*4 + {2,3}, tq=0
      *reinterpret_cast<bf16x8*>(rl + (h * 4 + 2) * 512) = f0;
      *reinterpret_cast<bf16x8*>(rl + (h * 4 + 3) * 512) = f1;
      tile2frag(r11, hi, &f0, &f1);   // td1, tp1 -> tq=1
      *reinterpret_cast<bf16x8*>(rl + 16384 + (h * 4 + 2) * 512) = f0;
      *reinterpret_cast<bf16x8*>(rl + 16384 + (h * 4 + 3) * 512) = f1;
    }
  }

  __syncthreads();  // drain R stores (vmcnt 0) + barrier: R visible block-wide

  // ---- Phase F: out = R @ Wo^T (+bo); wave w owns cols 128w..128w+127.
  // All 8 C-tiles accumulate simultaneously in AGPRs; explicit per-kc dbuf
  // prefetch of r/wo streams (48 arch regs; ~4 KiB in flight per 8 MFMAs).
  f32x16 acc[2][2][2];   // [pass][j][tq] — all indices compile-time
#pragma unroll
  for (int p2 = 0; p2 < 2; ++p2)
#pragma unroll
    for (int j = 0; j < 2; ++j)
#pragma unroll
      for (int tq = 0; tq < 2; ++tq)
        acc[p2][j][tq] = z16();
  {
    const unsigned short* rl = Rws + lane * 8;
    const unsigned short* wp = Wbf + (size_t)(24 + 2 * w) * 32768 + lane * 8;
    bf16x8 rb[2][2], wob[2][4];   // [buf][stream]
    rb[0][0] = *reinterpret_cast<const bf16x8*>(rl);
    rb[0][1] = *reinterpret_cast<const bf16x8*>(rl + 16384);
    wob[0][0] = *reinterpret_cast<const bf16x8*>(wp);
    wob[0][1] = *reinterpret_cast<const bf16x8*>(wp + 16384);
    wob[0][2] = *reinterpret_cast<const bf16x8*>(wp + 32768);
    wob[0][3] = *reinterpret_cast<const bf16x8*>(wp + 49152);
#pragma unroll
    for (int kc = 0; kc < 32; ++kc) {
      const int cur = kc & 1, nxt = cur ^ 1;
      if (kc < 31) {
        rb[nxt][0] = *reinterpret_cast<const bf16x8*>(rl + (kc + 1) * 512);
        rb[nxt][1] = *reinterpret_cast<const bf16x8*>(rl + 16384 + (kc + 1) * 512);
        wob[nxt][0] = *reinterpret_cast<const bf16x8*>(wp + (kc + 1) * 512);
        wob[nxt][1] = *reinterpret_cast<const bf16x8*>(wp + 16384 + (kc + 1) * 512);
        wob[nxt][2] = *reinterpret_cast<const bf16x8*>(wp + 32768 + (kc + 1) * 512);
        wob[nxt][3] = *reinterpret_cast<const bf16x8*>(wp + 49152 + (kc + 1) * 512);
      }
      acc[0][0][0] = MFMA32(rb[cur][0], wob[cur][0], acc[0][0][0]);
      acc[0][0][1] = MFMA32(rb[cur][1], wob[cur][0], acc[0][0][1]);
      acc[0][1][0] = MFMA32(rb[cur][0], wob[cur][1], acc[0][1][0]);
      acc[0][1][1] = MFMA32(rb[cur][1], wob[cur][1], acc[0][1][1]);
      acc[1][0][0] = MFMA32(rb[cur][0], wob[cur][2], acc[1][0][0]);
      acc[1][0][1] = MFMA32(rb[cur][1], wob[cur][2], acc[1][0][1]);
      acc[1][1][0] = MFMA32(rb[cur][0], wob[cur][3], acc[1][1][0]);
      acc[1][1][1] = MFMA32(rb[cur][1], wob[cur][3], acc[1][1][1]);
    }
  }
  __syncthreads();  // all waves done READING R; slot may now be overwritten

  float* og = out + (size_t)bid * 32768;
#pragma unroll
  for (int pass = 0; pass < 2; ++pass) {
#pragma unroll
    for (int j = 0; j < 2; ++j) {
      int col0 = 128 * w + 64 * pass + 32 * j + l31;
      float bov = bo[col0];
#pragma unroll
      for (int tq = 0; tq < 2; ++tq) {
        const f32x16& t = acc[pass][j][tq];
#pragma unroll
        for (int r = 0; r < 16; ++r) {
          int p = (r & 3) + 8 * (r >> 2) + 4 * hi + 32 * tq;
          og[p * 512 + col0] = t[r] + bov;
        }
      }
    }
  }
}

extern "C" void kernel_launch(void* const* d_in, const int* in_sizes, int n_in,
                              void* d_out, int out_size, void* d_ws, size_t ws_size,
                              hipStream_t stream) {
  const float* patches = (const float*)d_in[0];
  const float* Wq = (const float*)d_in[1];
  const float* bq = (const float*)d_in[2];
  const float* Wk = (const float*)d_in[3];
  const float* bk = (const float*)d_in[4];
  const float* Wv = (const float*)d_in[5];
  const float* bv = (const float*)d_in[6];
  const float* Wo = (const float*)d_in[7];
  const float* bo = (const float*)d_in[8];
  const float* posb = (const float*)d_in[9];
  // mask (d_in[10]) / bias_idx (d_in[11],[12]) recomputed on device.
  unsigned short* wbf = (unsigned short*)d_ws;   // 2 MiB
  hipLaunchKernelGGL(prep_weights, dim3(512), dim3(256), 0, stream, Wq, Wk, Wv, Wo, wbf);
  hipLaunchKernelGGL(swin_fused, dim3(2048), dim3(256), 0, stream,
                     patches, bq, bk, bv, bo, posb, wbf, (float*)d_out);
}